// Round 15
// baseline (189.887 us; speedup 1.0000x reference)
//
#include <hip/hip_runtime.h>
#include <stdint.h>
#include <math.h>

#define BDIM   2
#define CDIM   16
#define INS    64
#define OUTS   20
#define NPTS   8000          // 20^3
#define TOTN   (BDIM*NPTS)   // 16000
#define MSPLIT 4800          // m < MSPLIT: MFMA path; m >= MSPLIT: VALU path
#define MCHV   640           // VALU chunk size (5 chunks)

using f64x4 = __attribute__((ext_vector_type(4))) double;

#define MFMA64(a, b, c) __builtin_amdgcn_mfma_f64_16x16x4f64((a), (b), (c), 0, 0, 0)

// ---------------- ws layout (bytes, all 8B-aligned) ----------------
// sfeat(-2x): 0        +2,048,000   (B,N,C) f64, pre-scaled by -2
// tfeat     : 2048000  +2,048,000   (B,N,C) f64
// t2        : 4096000  +128,000     (B,N)   f64
// pscore    : 4224000  +B*nchunk*N*8
// pidx      : ...      +B*nchunk*N*4
// lpart     : ...      +504
// ~8.06 MB at nchunk=20 (fits; 9.03 proven earlier)

// Separable trilinear resize 64^3 -> 20^3 (jax.image.resize trilinear,
// antialias=True). Verified round 13 (absmax 0.0, ~20 us). Unchanged.
__global__ __launch_bounds__(256) void k_resize(const float* __restrict__ src,
                                                const float* __restrict__ tgt,
                                                double* __restrict__ sfeat2,
                                                double* __restrict__ tfeat) {
    __shared__ double wts[OUTS][8];
    __shared__ int    st[OUTS];
    __shared__ int    cnt[OUTS];
    __shared__ double plane[INS * INS];          // 32 KB
    __shared__ double hplane[OUTS * INS];        // 10 KB

    int tid = threadIdx.x;
    if (tid < OUTS) {
        double sample = (tid + 0.5) * 3.2 - 0.5;
        int lo = (int)ceil(sample - 3.2);
        int hi = (int)floor(sample + 3.2);
        if (lo < 0) lo = 0;
        if (hi > INS - 1) hi = INS - 1;
        int c = hi - lo + 1;           // <= 7
        double w[8];
        double sum = 0.0;
        for (int k = 0; k < 8; ++k) {
            double ww = 0.0;
            if (k < c) {
                double x = fabs(sample - (double)(lo + k)) * (1.0 / 3.2);
                ww = (x < 1.0) ? (1.0 - x) : 0.0;
            }
            w[k] = ww; sum += ww;
        }
        for (int k = 0; k < 8; ++k) wts[tid][k] = w[k] / sum;
        st[tid] = lo; cnt[tid] = c;
    }
    __syncthreads();

    int od  = blockIdx.x;                        // 0..19
    int c   = blockIdx.y;                        // 0..15
    int sb  = blockIdx.z;                        // 0..3
    int sel = sb >> 1;
    int b   = sb & 1;

    const float* in = (sel ? tgt : src) + (((size_t)(b * CDIM + c)) << 18);

    int sd = st[od], cd = cnt[od];
    double acc[16];
#pragma unroll
    for (int i = 0; i < 16; ++i) acc[i] = 0.0;
    for (int t = 0; t < cd; ++t) {
        double wd = wts[od][t];
        const float* p = in + (((size_t)(sd + t)) << 12) + tid;
#pragma unroll
        for (int i = 0; i < 16; ++i)
            acc[i] = fma(wd, (double)p[i << 8], acc[i]);
    }
#pragma unroll
    for (int i = 0; i < 16; ++i) plane[tid + (i << 8)] = acc[i];
    __syncthreads();

    for (int e = tid; e < OUTS * INS; e += 256) {
        int oh = e >> 6, w = e & 63;
        int sh = st[oh], ch = cnt[oh];
        double a = 0.0;
        for (int t = 0; t < ch; ++t)
            a = fma(wts[oh][t], plane[((sh + t) << 6) + w], a);
        hplane[e] = a;
    }
    __syncthreads();

    double* outf = sel ? tfeat : sfeat2;
    for (int e = tid; e < OUTS * OUTS; e += 256) {
        int oh = e / OUTS, ow = e - oh * OUTS;
        int sw = st[ow], cw = cnt[ow];
        const double* hp = &hplane[(oh << 6) + sw];
        double a = 0.0;
        for (int t = 0; t < cw; ++t)
            a = fma(wts[ow][t], hp[t], a);
        if (sel == 0) a = -2.0 * a;              // exact scale
        int n = (od * OUTS + oh) * OUTS + ow;
        outf[((size_t)(b * NPTS + n)) * CDIM + c] = a;
    }
}

__global__ void k_t2(const double* __restrict__ tfeat, double* __restrict__ t2) {
    int i = blockIdx.x * blockDim.x + threadIdx.x;
    if (i >= TOTN) return;
    const double* p = tfeat + (size_t)i * CDIM;
    double a = 0, b = 0, c = 0, d = 0;
#pragma unroll
    for (int k = 0; k < 4; ++k) {
        a = fma(p[4*k+0], p[4*k+0], a);
        b = fma(p[4*k+1], p[4*k+1], b);
        c = fma(p[4*k+2], p[4*k+2], c);
        d = fma(p[4*k+3], p[4*k+3], d);
    }
    t2[i] = (a + b) + (c + d);
}

// HYBRID argmin: chunks [0, nchunkM) = MFMA path (round-13 code, m in
// [0, MSPLIT)); chunks [nchunkM, nchunkM+nchunkV) = VALU path (round-6
// scalar code on the -2-prescaled features, m in [MSPLIT, 8000)).
// Mixed block types co-reside per CU and drive the (independent) MFMA and
// VALU pipes concurrently (m114). Chunk index ascends with m, every merge
// is lexicographic (score, m) -> exact first-occurrence argmin per path;
// cross-path exact ties would need bit-identical d2 across different fma
// orders (measure-zero for random floats).
__global__ __launch_bounds__(256, 2) void k_argmin(const double* __restrict__ sfeat2,
                                                   const double* __restrict__ tfeat,
                                                   const double* __restrict__ t2,
                                                   double* __restrict__ pscore,
                                                   int* __restrict__ pidx,
                                                   int mchunk, int nchunkM,
                                                   int nchunk) {
    __shared__ int    ptab[16];
    __shared__ double sc[1024];
    __shared__ int    smi[1024];

    int b     = blockIdx.z;
    int chunk = blockIdx.y;
    int lane  = threadIdx.x & 63;

    const double* tb  = tfeat + (size_t)b * NPTS * CDIM;
    const double* t2b = t2 + (size_t)b * NPTS;

    if (chunk < nchunkM) {
        // ================= MFMA path (round-13, verified) =================
        int wp    = threadIdx.x >> 6;                // 0..3
        int nbase = blockIdx.x << 7;                 // 128 n per block
        int n0    = nbase + (wp << 4);
        int n1    = n0 + 64;
        int lr    = lane & 15;
        int lq    = lane >> 4;

        f64x4 z = {0.0, 0.0, 0.0, 0.0};
        f64x4 calA = MFMA64((double)lr, 0.25, z);
        f64x4 calB = MFMA64(0.25, (double)lr, z);
        int ncol = (int)(calB[0] + 0.5);

#pragma unroll
        for (int j = 0; j < 4; ++j) {
            int r = (int)(calA[j] + 0.5);
            ptab[r] = (lq << 2) + j;
        }
        __syncthreads();
        int prow = ptab[lr];

        int nn0 = n0 + lr; if (nn0 > NPTS - 1) nn0 = NPTS - 1;
        int nn1 = n1 + lr; if (nn1 > NPTS - 1) nn1 = NPTS - 1;
        const double* sb0 = sfeat2 + ((size_t)(b * NPTS + nn0)) * CDIM + (lq << 2);
        const double* sb1 = sfeat2 + ((size_t)(b * NPTS + nn1)) * CDIM + (lq << 2);
        double b00 = sb0[0], b01 = sb0[1], b02 = sb0[2], b03 = sb0[3];
        double b10 = sb1[0], b11 = sb1[1], b12 = sb1[2], b13 = sb1[3];

        int mbase = chunk * mchunk;
        int iters = mchunk >> 5;

        const double* tA = tb + ((size_t)(mbase + prow)) * CDIM + (lq << 2);
        const double* tV = t2b + mbase + (lq << 2);

        double bs00 = 1e300, bs01 = 1e300, bs10 = 1e300, bs11 = 1e300;
        int    ip00 = 0, ip01 = 0, ip10 = 0, ip11 = 0;
        int    ij00 = 0, ij01 = 0, ij10 = 0, ij11 = 0;

        f64x4 aE0, aE1, vE0, vE1, aO0, aO1, vO0, vO1;

#define LOADP(P, A0, A1, V0, V1)                                   \
    {  const double* pa_ = tA + (size_t)((P) << 5) * CDIM;         \
       A0 = *(const f64x4*)(pa_);                                  \
       A1 = *(const f64x4*)(pa_ + (CDIM << 4));                    \
       const double* pv_ = tV + ((P) << 5);                        \
       V0 = *(const f64x4*)(pv_);                                  \
       V1 = *(const f64x4*)(pv_ + 16); }

#define FOLD(AC, BS, IP, IJ, P)                                    \
    {  double jb_ = AC[0]; int jj_ = 0;                            \
       if (AC[1] < jb_) { jb_ = AC[1]; jj_ = 1; }                  \
       if (AC[2] < jb_) { jb_ = AC[2]; jj_ = 2; }                  \
       if (AC[3] < jb_) { jb_ = AC[3]; jj_ = 3; }                  \
       if (jb_ < BS) { BS = jb_; IP = (P); IJ = jj_; } }

#define BODYP(P, A0, A1, V0, V1)                                   \
    {  f64x4 a00 = V0, a01 = V1, a10 = V0, a11 = V1;               \
       a00 = MFMA64(A0[0], b00, a00);                              \
       a10 = MFMA64(A0[0], b10, a10);                              \
       a01 = MFMA64(A1[0], b00, a01);                              \
       a11 = MFMA64(A1[0], b10, a11);                              \
       a00 = MFMA64(A0[1], b01, a00);                              \
       a10 = MFMA64(A0[1], b11, a10);                              \
       a01 = MFMA64(A1[1], b01, a01);                              \
       a11 = MFMA64(A1[1], b11, a11);                              \
       a00 = MFMA64(A0[2], b02, a00);                              \
       a10 = MFMA64(A0[2], b12, a10);                              \
       a01 = MFMA64(A1[2], b02, a01);                              \
       a11 = MFMA64(A1[2], b12, a11);                              \
       a00 = MFMA64(A0[3], b03, a00);                              \
       a10 = MFMA64(A0[3], b13, a10);                              \
       a01 = MFMA64(A1[3], b03, a01);                              \
       a11 = MFMA64(A1[3], b13, a11);                              \
       FOLD(a00, bs00, ip00, ij00, P)                              \
       FOLD(a01, bs01, ip01, ij01, P)                              \
       FOLD(a10, bs10, ip10, ij10, P)                              \
       FOLD(a11, bs11, ip11, ij11, P) }

        LOADP(0, aE0, aE1, vE0, vE1);
        if (iters > 1) LOADP(1, aO0, aO1, vO0, vO1);

        int p = 0;
        for (; p + 2 < iters; p += 2) {
            BODYP(p, aE0, aE1, vE0, vE1);
            LOADP(p + 2, aE0, aE1, vE0, vE1);
            BODYP(p + 1, aO0, aO1, vO0, vO1);
            if (p + 3 < iters) LOADP(p + 3, aO0, aO1, vO0, vO1);
        }
        BODYP(p, aE0, aE1, vE0, vE1);
        if (p + 1 < iters) BODYP(p + 1, aO0, aO1, vO0, vO1);

#undef LOADP
#undef FOLD
#undef BODYP

        int m00 = mbase + (ip00 << 5) + (lq << 2) + ij00;
        int m01 = mbase + (ip01 << 5) + 16 + (lq << 2) + ij01;
        int m10 = mbase + (ip10 << 5) + (lq << 2) + ij10;
        int m11 = mbase + (ip11 << 5) + 16 + (lq << 2) + ij11;

        double fb0 = bs00; int fm0 = m00;
        if (bs01 < fb0 || (bs01 == fb0 && m01 < fm0)) { fb0 = bs01; fm0 = m01; }
        double fb1 = bs10; int fm1 = m10;
        if (bs11 < fb1 || (bs11 == fb1 && m11 < fm1)) { fb1 = bs11; fm1 = m11; }

#pragma unroll
        for (int off = 16; off <= 32; off <<= 1) {
            double ob = __shfl_xor(fb0, off, 64);
            int    om = __shfl_xor(fm0, off, 64);
            if (ob < fb0 || (ob == fb0 && om < fm0)) { fb0 = ob; fm0 = om; }
            double ob1 = __shfl_xor(fb1, off, 64);
            int    om1 = __shfl_xor(fm1, off, 64);
            if (ob1 < fb1 || (ob1 == fb1 && om1 < fm1)) { fb1 = ob1; fm1 = om1; }
        }
        if (lq == 0) {
            size_t base = ((size_t)(b * nchunk + chunk)) * NPTS;
            int ns0 = n0 + ncol;
            pscore[base + ns0] = fb0;
            pidx[base + ns0]   = fm0;
            int ns1 = n1 + ncol;
            if (ns1 < NPTS) {
                pscore[base + ns1] = fb1;
                pidx[base + ns1]   = fm1;
            }
        }
    } else {
        // ================= VALU path (round-6 scalar, verified) ===========
        int bx = blockIdx.x;
        if (bx >= 32) return;                    // 32 blocks x 256 n cover N
        int nbase = bx << 8;
        int wp = (int)__builtin_amdgcn_readfirstlane(threadIdx.x >> 6);

        double s[4][16];                         // holds -2*s (prescaled)
#pragma unroll
        for (int j = 0; j < 4; ++j) {
            int n = nbase + lane + (j << 6);
            if (n > NPTS - 1) n = NPTS - 1;
            const double* sr = sfeat2 + ((size_t)(b * NPTS + n)) * CDIM;
#pragma unroll
            for (int k = 0; k < CDIM; ++k) s[j][k] = sr[k];
        }

        int vch   = chunk - nchunkM;
        int mbase = MSPLIT + vch * MCHV;
        double best[4] = {1e300, 1e300, 1e300, 1e300};
        int    bm[4]   = {0, 0, 0, 0};
        int mstart = mbase + wp;

#pragma unroll 2
        for (int i = 0; i < MCHV / 4; ++i) {
            int m = mstart + (i << 2);           // SGPR arithmetic
            const double* tr = tb + (size_t)m * CDIM;
            double t[16];
#pragma unroll
            for (int k = 0; k < CDIM; ++k) t[k] = tr[k];   // uniform -> s_load
            double t2v = t2b[m];
#pragma unroll
            for (int j = 0; j < 4; ++j) {
                double d0 = 0, d1 = 0, d2 = 0, d3 = 0;
#pragma unroll
                for (int k = 0; k < 4; ++k) {
                    d0 = fma(s[j][4*k+0], t[4*k+0], d0);
                    d1 = fma(s[j][4*k+1], t[4*k+1], d1);
                    d2 = fma(s[j][4*k+2], t[4*k+2], d2);
                    d3 = fma(s[j][4*k+3], t[4*k+3], d3);
                }
                double dot   = (d0 + d1) + (d2 + d3);
                double score = t2v + dot;        // s prescaled by -2
                if (score < best[j]) { best[j] = score; bm[j] = m; }
            }
        }

        // merge the 4 waves' candidates for the block's 256 n (lexicographic)
#pragma unroll
        for (int j = 0; j < 4; ++j) {
            sc [wp * 256 + lane * 4 + j] = best[j];
            smi[wp * 256 + lane * 4 + j] = bm[j];
        }
        __syncthreads();

        int tid = threadIdx.x;
        int e   = (tid & 63) * 4 + (tid >> 6);
        double b0 = sc[e];
        int    i0 = smi[e];
#pragma unroll
        for (int p = 1; p < 4; ++p) {
            double bp = sc[p * 256 + e];
            int    ip = smi[p * 256 + e];
            if (bp < b0 || (bp == b0 && ip < i0)) { b0 = bp; i0 = ip; }
        }
        int n = nbase + tid;
        if (n < NPTS) {
            size_t o = ((size_t)(b * nchunk + chunk)) * NPTS + n;
            pscore[o] = b0;
            pidx[o]   = i0;
        }
    }
}

// Merge chunks (ascending index == ascending m, lexicographic) + partial loss.
__global__ void k_mergeloss(const double* __restrict__ pscore,
                            const int* __restrict__ pidx,
                            const float* __restrict__ expd,
                            double* __restrict__ lpart, int nchunk) {
    int gid = blockIdx.x * 256 + threadIdx.x;    // 63*256 = 16128 >= 16000
    double sum = 0.0;
    if (gid < TOTN) {
        int b  = gid / NPTS;
        int nn = gid % NPTS;
        size_t o = ((size_t)(b * nchunk)) * NPTS + nn;
        double b0 = pscore[o];
        int    i0 = pidx[o];
        for (int c = 1; c < nchunk; ++c) {
            double bpv = pscore[o + (size_t)c * NPTS];
            int    ip  = pidx[o + (size_t)c * NPTS];
            if (bpv < b0 || (bpv == b0 && ip < i0)) { b0 = bpv; i0 = ip; }
        }
        double fd = (double)(i0 / 400);
        double fh = (double)((i0 / 20) % 20);
        double fw = (double)(i0 % 20);
        const float* e = expd + (size_t)gid * 3;
        sum = fabs((double)e[0] - fd) + fabs((double)e[1] - fh) + fabs((double)e[2] - fw);
    }
    __shared__ double red[256];
    red[threadIdx.x] = sum;
    __syncthreads();
    for (int s = 128; s > 0; s >>= 1) {
        if (threadIdx.x < s) red[threadIdx.x] += red[threadIdx.x + s];
        __syncthreads();
    }
    if (threadIdx.x == 0) lpart[blockIdx.x] = red[0];
}

__global__ void k_final(const double* __restrict__ lpart, float* __restrict__ out) {
    int lane = threadIdx.x;                      // 64
    double v = (lane < 63) ? lpart[lane] : 0.0;
#pragma unroll
    for (int off = 32; off > 0; off >>= 1) v += __shfl_down(v, off);
    if (lane == 0) out[0] = (float)(v / 48000.0);
}

extern "C" void kernel_launch(void* const* d_in, const int* in_sizes, int n_in,
                              void* d_out, int out_size, void* d_ws, size_t ws_size,
                              hipStream_t stream) {
    const float* src  = (const float*)d_in[0];
    const float* tgt  = (const float*)d_in[1];
    const float* expd = (const float*)d_in[2];

    // Hybrid: 15 MFMA chunks (m<4800, 320 m each) + 5 VALU chunks (640 m each).
    // Needs ~8.06 MB scratch; fall back to pure-MFMA nchunk=5 if short.
    int nchunkM = 15, mchunkM = 320, nchunkV = 5;
    int nchunk  = nchunkM + nchunkV;
    {
        size_t need = 4224000ull + (size_t)BDIM * 20 * NPTS * 12 + 512;
        if (ws_size < need) { nchunkM = 5; mchunkM = 1600; nchunkV = 0; nchunk = 5; }
    }

    char* ws = (char*)d_ws;
    double* sfeat2 = (double*)(ws);
    double* tfeat  = (double*)(ws + 2048000);
    double* t2     = (double*)(ws + 4096000);
    double* pscore = (double*)(ws + 4224000);
    size_t  psz    = (size_t)BDIM * nchunk * NPTS * 8;
    int*    pidx   = (int*)(ws + 4224000 + psz);
    size_t  isz    = (size_t)BDIM * nchunk * NPTS * 4;
    double* lpart  = (double*)(ws + 4224000 + psz + isz);

    k_resize   <<<dim3(OUTS, CDIM, 4), 256, 0, stream>>>(src, tgt, sfeat2, tfeat);
    k_t2       <<<63, 256, 0, stream>>>(tfeat, t2);
    k_argmin   <<<dim3(63, nchunk, BDIM), 256, 0, stream>>>(sfeat2, tfeat, t2,
                                                            pscore, pidx,
                                                            mchunkM, nchunkM, nchunk);
    k_mergeloss<<<63, 256, 0, stream>>>(pscore, pidx, expd, lpart, nchunk);
    k_final    <<<1, 64, 0, stream>>>(lpart, (float*)d_out);
}

// Round 16
// 184.321 us; speedup vs baseline: 1.0302x; 1.0302x over previous
//
#include <hip/hip_runtime.h>
#include <stdint.h>
#include <math.h>

#define BDIM   2
#define CDIM   16
#define INS    64
#define OUTS   20
#define NPTS   8000          // 20^3
#define TOTN   (BDIM*NPTS)   // 16000
#define MSPLIT 4800          // m < MSPLIT: MFMA path; m >= MSPLIT: VALU path
#define MCHV   640           // VALU chunk size (5 chunks)

using f64x4 = __attribute__((ext_vector_type(4))) double;

#define MFMA64(a, b, c) __builtin_amdgcn_mfma_f64_16x16x4f64((a), (b), (c), 0, 0, 0)

// ---------------- ws layout (bytes, all 8B-aligned) ----------------
// sfeat(-2x): 0        +2,048,000   (B,N,C) f64, pre-scaled by -2
// tfeat     : 2048000  +2,048,000   (B,N,C) f64
// t2        : 4096000  +128,000     (B,N)   f64
// pscore    : 4224000  +B*nchunk*N*8
// pidx      : ...      +B*nchunk*N*4
// lpart     : ...      +504
// ~8.06 MB at nchunk=20

// Separable trilinear resize 64^3 -> 20^3 (jax.image.resize trilinear,
// antialias=True). Verified round 13 (absmax 0.0, ~20 us). Unchanged.
__global__ __launch_bounds__(256) void k_resize(const float* __restrict__ src,
                                                const float* __restrict__ tgt,
                                                double* __restrict__ sfeat2,
                                                double* __restrict__ tfeat) {
    __shared__ double wts[OUTS][8];
    __shared__ int    st[OUTS];
    __shared__ int    cnt[OUTS];
    __shared__ double plane[INS * INS];          // 32 KB
    __shared__ double hplane[OUTS * INS];        // 10 KB

    int tid = threadIdx.x;
    if (tid < OUTS) {
        double sample = (tid + 0.5) * 3.2 - 0.5;
        int lo = (int)ceil(sample - 3.2);
        int hi = (int)floor(sample + 3.2);
        if (lo < 0) lo = 0;
        if (hi > INS - 1) hi = INS - 1;
        int c = hi - lo + 1;           // <= 7
        double w[8];
        double sum = 0.0;
        for (int k = 0; k < 8; ++k) {
            double ww = 0.0;
            if (k < c) {
                double x = fabs(sample - (double)(lo + k)) * (1.0 / 3.2);
                ww = (x < 1.0) ? (1.0 - x) : 0.0;
            }
            w[k] = ww; sum += ww;
        }
        for (int k = 0; k < 8; ++k) wts[tid][k] = w[k] / sum;
        st[tid] = lo; cnt[tid] = c;
    }
    __syncthreads();

    int od  = blockIdx.x;                        // 0..19
    int c   = blockIdx.y;                        // 0..15
    int sb  = blockIdx.z;                        // 0..3
    int sel = sb >> 1;
    int b   = sb & 1;

    const float* in = (sel ? tgt : src) + (((size_t)(b * CDIM + c)) << 18);

    int sd = st[od], cd = cnt[od];
    double acc[16];
#pragma unroll
    for (int i = 0; i < 16; ++i) acc[i] = 0.0;
    for (int t = 0; t < cd; ++t) {
        double wd = wts[od][t];
        const float* p = in + (((size_t)(sd + t)) << 12) + tid;
#pragma unroll
        for (int i = 0; i < 16; ++i)
            acc[i] = fma(wd, (double)p[i << 8], acc[i]);
    }
#pragma unroll
    for (int i = 0; i < 16; ++i) plane[tid + (i << 8)] = acc[i];
    __syncthreads();

    for (int e = tid; e < OUTS * INS; e += 256) {
        int oh = e >> 6, w = e & 63;
        int sh = st[oh], ch = cnt[oh];
        double a = 0.0;
        for (int t = 0; t < ch; ++t)
            a = fma(wts[oh][t], plane[((sh + t) << 6) + w], a);
        hplane[e] = a;
    }
    __syncthreads();

    double* outf = sel ? tfeat : sfeat2;
    for (int e = tid; e < OUTS * OUTS; e += 256) {
        int oh = e / OUTS, ow = e - oh * OUTS;
        int sw = st[ow], cw = cnt[ow];
        const double* hp = &hplane[(oh << 6) + sw];
        double a = 0.0;
        for (int t = 0; t < cw; ++t)
            a = fma(wts[ow][t], hp[t], a);
        if (sel == 0) a = -2.0 * a;              // exact scale
        int n = (od * OUTS + oh) * OUTS + ow;
        outf[((size_t)(b * NPTS + n)) * CDIM + c] = a;
    }
}

__global__ void k_t2(const double* __restrict__ tfeat, double* __restrict__ t2) {
    int i = blockIdx.x * blockDim.x + threadIdx.x;
    if (i >= TOTN) return;
    const double* p = tfeat + (size_t)i * CDIM;
    double a = 0, b = 0, c = 0, d = 0;
#pragma unroll
    for (int k = 0; k < 4; ++k) {
        a = fma(p[4*k+0], p[4*k+0], a);
        b = fma(p[4*k+1], p[4*k+1], b);
        c = fma(p[4*k+2], p[4*k+2], c);
        d = fma(p[4*k+3], p[4*k+3], d);
    }
    t2[i] = (a + b) + (c + d);
}

// HYBRID argmin with INTERLEAVED chunk types (round-15 fix): blockIdx.y
// pattern [V M M M V M M M ...] so MFMA-path and VALU-path blocks are
// co-resident on every CU throughout (round 15 put all V chunks last ->
// pure serial tail, no overlap). Merge is lexicographic on the ACTUAL m
// stored per slot, so slot order is irrelevant to exactness.
__global__ __launch_bounds__(256, 2) void k_argmin(const double* __restrict__ sfeat2,
                                                   const double* __restrict__ tfeat,
                                                   const double* __restrict__ t2,
                                                   double* __restrict__ pscore,
                                                   int* __restrict__ pidx,
                                                   int mchunk, int nchunkV,
                                                   int nchunk) {
    __shared__ int    ptab[16];
    __shared__ double sc[1024];
    __shared__ int    smi[1024];

    int b     = blockIdx.z;
    int chunk = blockIdx.y;
    int lane  = threadIdx.x & 63;

    // interleave decode: V at y%4==0 (when hybrid enabled), else M
    bool isV; int idx;
    if (nchunkV > 0 && (chunk & 3) == 0) { isV = true;  idx = chunk >> 2; }
    else if (nchunkV > 0)                { isV = false; idx = chunk - ((chunk + 3) >> 2); }
    else                                 { isV = false; idx = chunk; }

    const double* tb  = tfeat + (size_t)b * NPTS * CDIM;
    const double* t2b = t2 + (size_t)b * NPTS;

    if (!isV) {
        // ================= MFMA path (round-13, verified) =================
        int wp    = threadIdx.x >> 6;                // 0..3
        int nbase = blockIdx.x << 7;                 // 128 n per block
        int n0    = nbase + (wp << 4);
        int n1    = n0 + 64;
        int lr    = lane & 15;
        int lq    = lane >> 4;

        f64x4 z = {0.0, 0.0, 0.0, 0.0};
        f64x4 calA = MFMA64((double)lr, 0.25, z);
        f64x4 calB = MFMA64(0.25, (double)lr, z);
        int ncol = (int)(calB[0] + 0.5);

#pragma unroll
        for (int j = 0; j < 4; ++j) {
            int r = (int)(calA[j] + 0.5);
            ptab[r] = (lq << 2) + j;
        }
        __syncthreads();
        int prow = ptab[lr];

        int nn0 = n0 + lr; if (nn0 > NPTS - 1) nn0 = NPTS - 1;
        int nn1 = n1 + lr; if (nn1 > NPTS - 1) nn1 = NPTS - 1;
        const double* sb0 = sfeat2 + ((size_t)(b * NPTS + nn0)) * CDIM + (lq << 2);
        const double* sb1 = sfeat2 + ((size_t)(b * NPTS + nn1)) * CDIM + (lq << 2);
        double b00 = sb0[0], b01 = sb0[1], b02 = sb0[2], b03 = sb0[3];
        double b10 = sb1[0], b11 = sb1[1], b12 = sb1[2], b13 = sb1[3];

        int mbase = idx * mchunk;
        int iters = mchunk >> 5;

        const double* tA = tb + ((size_t)(mbase + prow)) * CDIM + (lq << 2);
        const double* tV = t2b + mbase + (lq << 2);

        double bs00 = 1e300, bs01 = 1e300, bs10 = 1e300, bs11 = 1e300;
        int    ip00 = 0, ip01 = 0, ip10 = 0, ip11 = 0;
        int    ij00 = 0, ij01 = 0, ij10 = 0, ij11 = 0;

        f64x4 aE0, aE1, vE0, vE1, aO0, aO1, vO0, vO1;

#define LOADP(P, A0, A1, V0, V1)                                   \
    {  const double* pa_ = tA + (size_t)((P) << 5) * CDIM;         \
       A0 = *(const f64x4*)(pa_);                                  \
       A1 = *(const f64x4*)(pa_ + (CDIM << 4));                    \
       const double* pv_ = tV + ((P) << 5);                        \
       V0 = *(const f64x4*)(pv_);                                  \
       V1 = *(const f64x4*)(pv_ + 16); }

#define FOLD(AC, BS, IP, IJ, P)                                    \
    {  double jb_ = AC[0]; int jj_ = 0;                            \
       if (AC[1] < jb_) { jb_ = AC[1]; jj_ = 1; }                  \
       if (AC[2] < jb_) { jb_ = AC[2]; jj_ = 2; }                  \
       if (AC[3] < jb_) { jb_ = AC[3]; jj_ = 3; }                  \
       if (jb_ < BS) { BS = jb_; IP = (P); IJ = jj_; } }

#define BODYP(P, A0, A1, V0, V1)                                   \
    {  f64x4 a00 = V0, a01 = V1, a10 = V0, a11 = V1;               \
       a00 = MFMA64(A0[0], b00, a00);                              \
       a10 = MFMA64(A0[0], b10, a10);                              \
       a01 = MFMA64(A1[0], b00, a01);                              \
       a11 = MFMA64(A1[0], b10, a11);                              \
       a00 = MFMA64(A0[1], b01, a00);                              \
       a10 = MFMA64(A0[1], b11, a10);                              \
       a01 = MFMA64(A1[1], b01, a01);                              \
       a11 = MFMA64(A1[1], b11, a11);                              \
       a00 = MFMA64(A0[2], b02, a00);                              \
       a10 = MFMA64(A0[2], b12, a10);                              \
       a01 = MFMA64(A1[2], b02, a01);                              \
       a11 = MFMA64(A1[2], b12, a11);                              \
       a00 = MFMA64(A0[3], b03, a00);                              \
       a10 = MFMA64(A0[3], b13, a10);                              \
       a01 = MFMA64(A1[3], b03, a01);                              \
       a11 = MFMA64(A1[3], b13, a11);                              \
       FOLD(a00, bs00, ip00, ij00, P)                              \
       FOLD(a01, bs01, ip01, ij01, P)                              \
       FOLD(a10, bs10, ip10, ij10, P)                              \
       FOLD(a11, bs11, ip11, ij11, P) }

        LOADP(0, aE0, aE1, vE0, vE1);
        if (iters > 1) LOADP(1, aO0, aO1, vO0, vO1);

        int p = 0;
        for (; p + 2 < iters; p += 2) {
            BODYP(p, aE0, aE1, vE0, vE1);
            LOADP(p + 2, aE0, aE1, vE0, vE1);
            BODYP(p + 1, aO0, aO1, vO0, vO1);
            if (p + 3 < iters) LOADP(p + 3, aO0, aO1, vO0, vO1);
        }
        BODYP(p, aE0, aE1, vE0, vE1);
        if (p + 1 < iters) BODYP(p + 1, aO0, aO1, vO0, vO1);

#undef LOADP
#undef FOLD
#undef BODYP

        int m00 = mbase + (ip00 << 5) + (lq << 2) + ij00;
        int m01 = mbase + (ip01 << 5) + 16 + (lq << 2) + ij01;
        int m10 = mbase + (ip10 << 5) + (lq << 2) + ij10;
        int m11 = mbase + (ip11 << 5) + 16 + (lq << 2) + ij11;

        double fb0 = bs00; int fm0 = m00;
        if (bs01 < fb0 || (bs01 == fb0 && m01 < fm0)) { fb0 = bs01; fm0 = m01; }
        double fb1 = bs10; int fm1 = m10;
        if (bs11 < fb1 || (bs11 == fb1 && m11 < fm1)) { fb1 = bs11; fm1 = m11; }

#pragma unroll
        for (int off = 16; off <= 32; off <<= 1) {
            double ob = __shfl_xor(fb0, off, 64);
            int    om = __shfl_xor(fm0, off, 64);
            if (ob < fb0 || (ob == fb0 && om < fm0)) { fb0 = ob; fm0 = om; }
            double ob1 = __shfl_xor(fb1, off, 64);
            int    om1 = __shfl_xor(fm1, off, 64);
            if (ob1 < fb1 || (ob1 == fb1 && om1 < fm1)) { fb1 = ob1; fm1 = om1; }
        }
        if (lq == 0) {
            size_t base = ((size_t)(b * nchunk + chunk)) * NPTS;
            int ns0 = n0 + ncol;
            pscore[base + ns0] = fb0;
            pidx[base + ns0]   = fm0;
            int ns1 = n1 + ncol;
            if (ns1 < NPTS) {
                pscore[base + ns1] = fb1;
                pidx[base + ns1]   = fm1;
            }
        }
    } else {
        // ================= VALU path (round-6 scalar, verified) ===========
        int bx = blockIdx.x;
        if (bx >= 32) return;                    // 32 blocks x 256 n cover N
        int nbase = bx << 8;
        int wp = (int)__builtin_amdgcn_readfirstlane(threadIdx.x >> 6);

        double s[4][16];                         // holds -2*s (prescaled)
#pragma unroll
        for (int j = 0; j < 4; ++j) {
            int n = nbase + lane + (j << 6);
            if (n > NPTS - 1) n = NPTS - 1;
            const double* sr = sfeat2 + ((size_t)(b * NPTS + n)) * CDIM;
#pragma unroll
            for (int k = 0; k < CDIM; ++k) s[j][k] = sr[k];
        }

        int mbase = MSPLIT + idx * MCHV;
        double best[4] = {1e300, 1e300, 1e300, 1e300};
        int    bm[4]   = {0, 0, 0, 0};
        int mstart = mbase + wp;

#pragma unroll 2
        for (int i = 0; i < MCHV / 4; ++i) {
            int m = mstart + (i << 2);           // SGPR arithmetic
            const double* tr = tb + (size_t)m * CDIM;
            double t[16];
#pragma unroll
            for (int k = 0; k < CDIM; ++k) t[k] = tr[k];   // uniform -> s_load
            double t2v = t2b[m];
#pragma unroll
            for (int j = 0; j < 4; ++j) {
                double d0 = 0, d1 = 0, d2 = 0, d3 = 0;
#pragma unroll
                for (int k = 0; k < 4; ++k) {
                    d0 = fma(s[j][4*k+0], t[4*k+0], d0);
                    d1 = fma(s[j][4*k+1], t[4*k+1], d1);
                    d2 = fma(s[j][4*k+2], t[4*k+2], d2);
                    d3 = fma(s[j][4*k+3], t[4*k+3], d3);
                }
                double dot   = (d0 + d1) + (d2 + d3);
                double score = t2v + dot;        // s prescaled by -2
                if (score < best[j]) { best[j] = score; bm[j] = m; }
            }
        }

#pragma unroll
        for (int j = 0; j < 4; ++j) {
            sc [wp * 256 + lane * 4 + j] = best[j];
            smi[wp * 256 + lane * 4 + j] = bm[j];
        }
        __syncthreads();

        int tid = threadIdx.x;
        int e   = (tid & 63) * 4 + (tid >> 6);
        double b0 = sc[e];
        int    i0 = smi[e];
#pragma unroll
        for (int p = 1; p < 4; ++p) {
            double bp = sc[p * 256 + e];
            int    ip = smi[p * 256 + e];
            if (bp < b0 || (bp == b0 && ip < i0)) { b0 = bp; i0 = ip; }
        }
        int n = nbase + tid;
        if (n < NPTS) {
            size_t o = ((size_t)(b * nchunk + chunk)) * NPTS + n;
            pscore[o] = b0;
            pidx[o]   = i0;
        }
    }
}

// Merge chunk slots (lexicographic on actual (score, m)) + partial loss.
__global__ void k_mergeloss(const double* __restrict__ pscore,
                            const int* __restrict__ pidx,
                            const float* __restrict__ expd,
                            double* __restrict__ lpart, int nchunk) {
    int gid = blockIdx.x * 256 + threadIdx.x;    // 63*256 = 16128 >= 16000
    double sum = 0.0;
    if (gid < TOTN) {
        int b  = gid / NPTS;
        int nn = gid % NPTS;
        size_t o = ((size_t)(b * nchunk)) * NPTS + nn;
        double b0 = pscore[o];
        int    i0 = pidx[o];
        for (int c = 1; c < nchunk; ++c) {
            double bpv = pscore[o + (size_t)c * NPTS];
            int    ip  = pidx[o + (size_t)c * NPTS];
            if (bpv < b0 || (bpv == b0 && ip < i0)) { b0 = bpv; i0 = ip; }
        }
        double fd = (double)(i0 / 400);
        double fh = (double)((i0 / 20) % 20);
        double fw = (double)(i0 % 20);
        const float* e = expd + (size_t)gid * 3;
        sum = fabs((double)e[0] - fd) + fabs((double)e[1] - fh) + fabs((double)e[2] - fw);
    }
    __shared__ double red[256];
    red[threadIdx.x] = sum;
    __syncthreads();
    for (int s = 128; s > 0; s >>= 1) {
        if (threadIdx.x < s) red[threadIdx.x] += red[threadIdx.x + s];
        __syncthreads();
    }
    if (threadIdx.x == 0) lpart[blockIdx.x] = red[0];
}

__global__ void k_final(const double* __restrict__ lpart, float* __restrict__ out) {
    int lane = threadIdx.x;                      // 64
    double v = (lane < 63) ? lpart[lane] : 0.0;
#pragma unroll
    for (int off = 32; off > 0; off >>= 1) v += __shfl_down(v, off);
    if (lane == 0) out[0] = (float)(v / 48000.0);
}

extern "C" void kernel_launch(void* const* d_in, const int* in_sizes, int n_in,
                              void* d_out, int out_size, void* d_ws, size_t ws_size,
                              hipStream_t stream) {
    const float* src  = (const float*)d_in[0];
    const float* tgt  = (const float*)d_in[1];
    const float* expd = (const float*)d_in[2];

    // Hybrid: 15 MFMA chunks (m<4800, 320 m) + 5 VALU chunks (640 m),
    // interleaved [V M M M ...]. ~8.06 MB scratch; fallback: pure MFMA.
    int nchunkV = 5, mchunkM = 320;
    int nchunk  = 20;
    {
        size_t need = 4224000ull + (size_t)BDIM * 20 * NPTS * 12 + 512;
        if (ws_size < need) { nchunkV = 0; mchunkM = 1600; nchunk = 5; }
    }

    char* ws = (char*)d_ws;
    double* sfeat2 = (double*)(ws);
    double* tfeat  = (double*)(ws + 2048000);
    double* t2     = (double*)(ws + 4096000);
    double* pscore = (double*)(ws + 4224000);
    size_t  psz    = (size_t)BDIM * nchunk * NPTS * 8;
    int*    pidx   = (int*)(ws + 4224000 + psz);
    size_t  isz    = (size_t)BDIM * nchunk * NPTS * 4;
    double* lpart  = (double*)(ws + 4224000 + psz + isz);

    k_resize   <<<dim3(OUTS, CDIM, 4), 256, 0, stream>>>(src, tgt, sfeat2, tfeat);
    k_t2       <<<63, 256, 0, stream>>>(tfeat, t2);
    k_argmin   <<<dim3(63, nchunk, BDIM), 256, 0, stream>>>(sfeat2, tfeat, t2,
                                                            pscore, pidx,
                                                            mchunkM, nchunkV, nchunk);
    k_mergeloss<<<63, 256, 0, stream>>>(pscore, pidx, expd, lpart, nchunk);
    k_final    <<<1, 64, 0, stream>>>(lpart, (float*)d_out);
}